// Round 1
// baseline (313.985 us; speedup 1.0000x reference)
//
#include <hip/hip_runtime.h>

// ---------------------------------------------------------------------------
// SelfAttention: B=2,T=2048,D_IN=1024,E=64,H=16, causal, interleaved (E,H)
// Pipeline: cast -> W^T cast -> QKV MFMA GEMM -> head-layout -> flash attn -> out GEMM
// All bf16 storage is unsigned short (raw bits); MFMA via __bf16 vectors.
// ---------------------------------------------------------------------------

typedef __bf16 bf16x8 __attribute__((ext_vector_type(8)));
typedef float f32x4 __attribute__((ext_vector_type(4)));
typedef unsigned short u16;
typedef unsigned int u32;

__device__ __forceinline__ u16 f2bf(float f) {
    union { float f; u32 u; } v; v.f = f;
    u32 r = (v.u + 0x7FFFu + ((v.u >> 16) & 1u)) >> 16;   // RNE
    return (u16)r;
}

// ---------------- constants ----------------
#define BB 2
#define TT 2048
#define DIN 1024
#define EE 64
#define HH 16
#define NN 1024           // E*H
#define MM 4096           // B*T

// ---------------- kernel 1: cast inp -> bf16 ----------------
__global__ void cast_x(const float* __restrict__ in, u16* __restrict__ out, int n4) {
    int i = blockIdx.x * blockDim.x + threadIdx.x;
    if (i < n4) {
        float4 f = ((const float4*)in)[i];
        ushort4 o;
        o.x = f2bf(f.x); o.y = f2bf(f.y); o.z = f2bf(f.z); o.w = f2bf(f.w);
        ((ushort4*)out)[i] = o;
    }
}

// ---------------- kernel 2: W[k][n] fp32 -> Wt[n][k] bf16 ----------------
__global__ void transpose_w(const float* __restrict__ Wq, const float* __restrict__ Wk,
                            const float* __restrict__ Wv, const float* __restrict__ Wu,
                            u16* __restrict__ wqt, u16* __restrict__ wkt,
                            u16* __restrict__ wvt, u16* __restrict__ wut) {
    int z = blockIdx.z;
    const float* src; u16* dst; int N;
    if (z == 0)      { src = Wq; dst = wqt; N = 1024; }
    else if (z == 1) { src = Wk; dst = wkt; N = 1024; }
    else if (z == 2) { src = Wv; dst = wvt; N = 1024; }
    else             { src = Wu; dst = wut; N = 64; if (blockIdx.y >= 2) return; }
    __shared__ float lds[32][33];
    int k0 = blockIdx.x * 32, n0 = blockIdx.y * 32;
    int tid = threadIdx.x;
    int c = tid & 31, r0 = tid >> 5;
#pragma unroll
    for (int p = 0; p < 4; ++p) {
        int r = r0 + p * 8;
        lds[r][c] = src[(k0 + r) * N + n0 + c];
    }
    __syncthreads();
#pragma unroll
    for (int p = 0; p < 4; ++p) {
        int nr = r0 + p * 8;
        dst[(n0 + nr) * 1024 + k0 + c] = f2bf(lds[c][nr]);
    }
}

// ---------------- kernel 3: QKV GEMM: C[M,N] = Xb[M,K] * Wt[N,K]^T ----------------
// 128x128 tile, 4 waves (2x2), each wave 64x64 via 4x4 16x16x32 subtiles.
__global__ __launch_bounds__(256) void gemm_qkv(const u16* __restrict__ xb,
                                                const u16* __restrict__ wqt,
                                                const u16* __restrict__ wkt,
                                                const u16* __restrict__ wvt,
                                                u16* __restrict__ qd, u16* __restrict__ kd,
                                                u16* __restrict__ vd) {
    int z = blockIdx.z;
    const u16* wt = (z == 0) ? wqt : (z == 1) ? wkt : wvt;
    u16* dst      = (z == 0) ? qd  : (z == 1) ? kd  : vd;
    __shared__ u16 lA[128 * 32];
    __shared__ u16 lB[128 * 32];
    int tid = threadIdx.x;
    int m0 = blockIdx.x * 128, n0 = blockIdx.y * 128;
    int lane = tid & 63, w = tid >> 6;
    int wr = w >> 1, wc = w & 1;
    int l15 = lane & 15, quad = lane >> 4;
    f32x4 acc[4][4] = {};
    int row = tid >> 2, kcol = (tid & 3) * 8;   // staging: row in [0,64) per chunk
#pragma unroll 1
    for (int kk = 0; kk < 32; ++kk) {
        int kb = kk * 32;
        uint4 a0 = *(const uint4*)(xb + (m0 + row) * 1024 + kb + kcol);
        uint4 a1 = *(const uint4*)(xb + (m0 + 64 + row) * 1024 + kb + kcol);
        uint4 b0 = *(const uint4*)(wt + (n0 + row) * 1024 + kb + kcol);
        uint4 b1 = *(const uint4*)(wt + (n0 + 64 + row) * 1024 + kb + kcol);
        __syncthreads();
        *(uint4*)(lA + row * 32 + kcol) = a0;
        *(uint4*)(lA + (64 + row) * 32 + kcol) = a1;
        *(uint4*)(lB + row * 32 + kcol) = b0;
        *(uint4*)(lB + (64 + row) * 32 + kcol) = b1;
        __syncthreads();
        bf16x8 af[4], bfr[4];
#pragma unroll
        for (int i = 0; i < 4; ++i)
            af[i] = *(const bf16x8*)(lA + (wr * 64 + i * 16 + l15) * 32 + quad * 8);
#pragma unroll
        for (int j = 0; j < 4; ++j)
            bfr[j] = *(const bf16x8*)(lB + (wc * 64 + j * 16 + l15) * 32 + quad * 8);
#pragma unroll
        for (int i = 0; i < 4; ++i)
#pragma unroll
            for (int j = 0; j < 4; ++j)
                acc[i][j] = __builtin_amdgcn_mfma_f32_16x16x32_bf16(af[i], bfr[j], acc[i][j], 0, 0, 0);
    }
#pragma unroll
    for (int i = 0; i < 4; ++i)
#pragma unroll
        for (int j = 0; j < 4; ++j)
#pragma unroll
            for (int r = 0; r < 4; ++r) {
                int m = m0 + wr * 64 + i * 16 + quad * 4 + r;
                int n = n0 + wc * 64 + j * 16 + l15;
                dst[m * 1024 + n] = f2bf(acc[i][j][r]);
            }
}

// ---------------- kernel 4: head layout ----------------
// z=0/1: q/k [b][t][e*16+h] -> [b][h][t][e];  z=2: v -> [b][h][e][t]
__global__ void head_layout(const u16* __restrict__ qs, const u16* __restrict__ ks,
                            const u16* __restrict__ vs,
                            u16* __restrict__ qd, u16* __restrict__ kd, u16* __restrict__ vd) {
    int z = blockIdx.z;
    int by = blockIdx.y;            // b*H + h
    int b = by >> 4, h = by & 15;
    int t0 = blockIdx.x * 64;
    int tid = threadIdx.x;
    int e = tid & 63, ttb = tid >> 6;
    __shared__ u16 lds[64 * 66];
    if (z < 2) {
        const u16* src = (z == 0) ? qs : ks;
        u16* dst = (z == 0) ? qd : kd;
#pragma unroll
        for (int p = 0; p < 16; ++p) {
            int t = t0 + p * 4 + ttb;
            dst[(by * 2048 + t) * 64 + e] = src[(b * 2048 + t) * 1024 + e * 16 + h];
        }
    } else {
#pragma unroll
        for (int p = 0; p < 16; ++p) {
            int tt = p * 4 + ttb;
            lds[tt * 66 + e] = vs[(b * 2048 + t0 + tt) * 1024 + e * 16 + h];
        }
        __syncthreads();
        int tc = tid & 63, eb = tid >> 6;
#pragma unroll
        for (int p = 0; p < 16; ++p) {
            int er = p * 4 + eb;
            vd[(by * 64 + er) * 2048 + t0 + tc] = lds[tc * 66 + er];
        }
    }
}

// ---------------- kernel 5: flash attention ----------------
// grid (32 qtiles, 32 b*h). 4 waves, each owns a 16-row Q strip.
__global__ __launch_bounds__(256) void attn(const u16* __restrict__ qh, const u16* __restrict__ kh,
                                            const u16* __restrict__ vh, u16* __restrict__ ot) {
    __shared__ u16 sQ[64 * 72];
    __shared__ u16 sK[64 * 72];
    __shared__ u16 sV[64 * 72];   // V^T tile: [e][s]
    __shared__ u16 sP[4 * 16 * 72];
    int tid = threadIdx.x, lane = tid & 63, w = tid >> 6;
    int quad = lane >> 4, l15 = lane & 15;
    int qtile = (int)gridDim.x - 1 - (int)blockIdx.x;   // heavy blocks first
    int by = blockIdx.y;
    int b = by >> 4, h = by & 15;
    const int Tq0 = qtile * 64;
    // stage Q tile (rows pad to 72)
#pragma unroll
    for (int p = 0; p < 2; ++p) {
        int idx = p * 2048 + tid * 8;
        int tt = idx >> 6, e0 = idx & 63;
        uint4 v = *(const uint4*)(qh + (by * 2048 + Tq0 + tt) * 64 + e0);
        *(uint4*)(sQ + tt * 72 + e0) = v;
    }
    __syncthreads();
    bf16x8 aq[2];
    aq[0] = *(const bf16x8*)(sQ + (w * 16 + l15) * 72 + quad * 8);
    aq[1] = *(const bf16x8*)(sQ + (w * 16 + l15) * 72 + 32 + quad * 8);
    float mrow[4], lrow[4];
    f32x4 oacc[4] = {};
#pragma unroll
    for (int r = 0; r < 4; ++r) { mrow[r] = -3e38f; lrow[r] = 0.f; }

    for (int jt = 0; jt <= qtile; ++jt) {
        __syncthreads();   // prev-iter LDS consumers done
#pragma unroll
        for (int p = 0; p < 2; ++p) {
            int idx = p * 2048 + tid * 8;
            int rr = idx >> 6, c0 = idx & 63;
            uint4 kv = *(const uint4*)(kh + (by * 2048 + jt * 64 + rr) * 64 + c0);
            uint4 vv = *(const uint4*)(vh + (by * 64 + rr) * 2048 + jt * 64 + c0);
            *(uint4*)(sK + rr * 72 + c0) = kv;
            *(uint4*)(sV + rr * 72 + c0) = vv;
        }
        __syncthreads();
        // S = Q K^T for this wave's 16-row strip
        f32x4 sacc[4] = {};
#pragma unroll
        for (int j4 = 0; j4 < 4; ++j4)
#pragma unroll
            for (int k2 = 0; k2 < 2; ++k2) {
                bf16x8 bk = *(const bf16x8*)(sK + (j4 * 16 + l15) * 72 + k2 * 32 + quad * 8);
                sacc[j4] = __builtin_amdgcn_mfma_f32_16x16x32_bf16(aq[k2], bk, sacc[j4], 0, 0, 0);
            }
        bool diag = (jt == qtile);
#pragma unroll
        for (int j4 = 0; j4 < 4; ++j4)
#pragma unroll
            for (int r = 0; r < 4; ++r) {
                float s = sacc[j4][r] * 0.125f;
                if (diag) {
                    int sg = j4 * 16 + l15;
                    int tg = w * 16 + quad * 4 + r;
                    if (sg > tg) s = -1e30f;
                }
                sacc[j4][r] = s;
            }
        // online softmax per row (row = quad*4+r, 16 lanes of the quad hold cols)
        float pv[4][4];
#pragma unroll
        for (int r = 0; r < 4; ++r) {
            float mx = fmaxf(fmaxf(sacc[0][r], sacc[1][r]), fmaxf(sacc[2][r], sacc[3][r]));
#pragma unroll
            for (int off = 1; off < 16; off <<= 1) mx = fmaxf(mx, __shfl_xor(mx, off, 16));
            float mnew = fmaxf(mrow[r], mx);
            float alpha = __expf(mrow[r] - mnew);
            float rs = 0.f;
#pragma unroll
            for (int j4 = 0; j4 < 4; ++j4) {
                float p = __expf(sacc[j4][r] - mnew);
                pv[j4][r] = p; rs += p;
            }
#pragma unroll
            for (int off = 1; off < 16; off <<= 1) rs += __shfl_xor(rs, off, 16);
            lrow[r] = lrow[r] * alpha + rs;
            mrow[r] = mnew;
#pragma unroll
            for (int e4 = 0; e4 < 4; ++e4) oacc[e4][r] *= alpha;
        }
        // P: C-layout -> LDS -> A-layout (per-wave region, no barrier needed)
#pragma unroll
        for (int j4 = 0; j4 < 4; ++j4)
#pragma unroll
            for (int r = 0; r < 4; ++r)
                sP[(w * 16 + quad * 4 + r) * 72 + j4 * 16 + l15] = f2bf(pv[j4][r]);
        bf16x8 ap[2];
        ap[0] = *(const bf16x8*)(sP + (w * 16 + l15) * 72 + quad * 8);
        ap[1] = *(const bf16x8*)(sP + (w * 16 + l15) * 72 + 32 + quad * 8);
#pragma unroll
        for (int e4 = 0; e4 < 4; ++e4)
#pragma unroll
            for (int k2 = 0; k2 < 2; ++k2) {
                bf16x8 bv = *(const bf16x8*)(sV + (e4 * 16 + l15) * 72 + k2 * 32 + quad * 8);
                oacc[e4] = __builtin_amdgcn_mfma_f32_16x16x32_bf16(ap[k2], bv, oacc[e4], 0, 0, 0);
            }
    }
    // epilogue: normalize and store interleaved [b][t][e*16+h]
#pragma unroll
    for (int r = 0; r < 4; ++r) {
        float inv = 1.f / lrow[r];
        int t = Tq0 + w * 16 + quad * 4 + r;
#pragma unroll
        for (int e4 = 0; e4 < 4; ++e4) {
            int e = e4 * 16 + l15;
            ot[(b * 2048 + t) * 1024 + e * 16 + h] = f2bf(oacc[e4][r] * inv);
        }
    }
}

// ---------------- kernel 6: out = ot[M,1024] @ Wu + bu (fp32 out, N=64) ----------------
__global__ __launch_bounds__(256) void gemm_out(const u16* __restrict__ ot, const u16* __restrict__ wut,
                                                const float* __restrict__ bu, float* __restrict__ out) {
    __shared__ u16 lA[64 * 32];
    __shared__ u16 lB[64 * 32];
    int tid = threadIdx.x, lane = tid & 63, w = tid >> 6;
    int quad = lane >> 4, l15 = lane & 15;
    int m0 = blockIdx.x * 64;
    f32x4 acc[4] = {};
    int row = tid >> 2, kcol = (tid & 3) * 8;
#pragma unroll 1
    for (int kk = 0; kk < 32; ++kk) {
        int kb = kk * 32;
        uint4 a0 = *(const uint4*)(ot + (m0 + row) * 1024 + kb + kcol);
        uint4 b0 = *(const uint4*)(wut + row * 1024 + kb + kcol);
        __syncthreads();
        *(uint4*)(lA + row * 32 + kcol) = a0;
        *(uint4*)(lB + row * 32 + kcol) = b0;
        __syncthreads();
        bf16x8 af = *(const bf16x8*)(lA + (w * 16 + l15) * 32 + quad * 8);
#pragma unroll
        for (int j = 0; j < 4; ++j) {
            bf16x8 bfr = *(const bf16x8*)(lB + (j * 16 + l15) * 32 + quad * 8);
            acc[j] = __builtin_amdgcn_mfma_f32_16x16x32_bf16(af, bfr, acc[j], 0, 0, 0);
        }
    }
#pragma unroll
    for (int j = 0; j < 4; ++j) {
        int n = j * 16 + l15;
        float bias = bu[n];
#pragma unroll
        for (int r = 0; r < 4; ++r) {
            int m = m0 + w * 16 + quad * 4 + r;
            out[m * 64 + n] = acc[j][r] + bias;
        }
    }
}

// ---------------- workspace layout (bytes) ----------------
#define OFF_XB   0u
#define OFF_WQT  8388608u
#define OFF_WKT  10485760u
#define OFF_WVT  12582912u
#define OFF_WUT  14680064u
#define OFF_QT   14811136u
#define OFF_KT   23199744u
#define OFF_VT   31588352u
#define OFF_QH   39976960u
#define OFF_KH   48365568u
#define OFF_VH   56754176u
#define OFF_OT   OFF_QT      /* alias: qt_ dead after head_layout */

extern "C" void kernel_launch(void* const* d_in, const int* in_sizes, int n_in,
                              void* d_out, int out_size, void* d_ws, size_t ws_size,
                              hipStream_t stream) {
    (void)in_sizes; (void)n_in; (void)out_size; (void)ws_size;
    const float* inp = (const float*)d_in[0];
    // d_in[1] = mask (causal triu) — implemented analytically, not read
    const float* Wq = (const float*)d_in[2];
    const float* Wk = (const float*)d_in[3];
    const float* Wv = (const float*)d_in[4];
    const float* Wu = (const float*)d_in[5];
    const float* bu = (const float*)d_in[6];
    float* out = (float*)d_out;
    char* ws = (char*)d_ws;
    u16* xb  = (u16*)(ws + OFF_XB);
    u16* wqt = (u16*)(ws + OFF_WQT);
    u16* wkt = (u16*)(ws + OFF_WKT);
    u16* wvt = (u16*)(ws + OFF_WVT);
    u16* wut = (u16*)(ws + OFF_WUT);
    u16* qt_ = (u16*)(ws + OFF_QT);
    u16* kt_ = (u16*)(ws + OFF_KT);
    u16* vt_ = (u16*)(ws + OFF_VT);
    u16* qh  = (u16*)(ws + OFF_QH);
    u16* kh  = (u16*)(ws + OFF_KH);
    u16* vh  = (u16*)(ws + OFF_VH);
    u16* ot  = (u16*)(ws + OFF_OT);

    cast_x<<<4096, 256, 0, stream>>>(inp, xb, (MM * DIN) / 4);
    transpose_w<<<dim3(32, 32, 4), 256, 0, stream>>>(Wq, Wk, Wv, Wu, wqt, wkt, wvt, wut);
    gemm_qkv<<<dim3(32, 8, 3), 256, 0, stream>>>(xb, wqt, wkt, wvt, qt_, kt_, vt_);
    head_layout<<<dim3(32, 32, 3), 256, 0, stream>>>(qt_, kt_, vt_, qh, kh, vh);
    attn<<<dim3(32, 32), 256, 0, stream>>>(qh, kh, vh, ot);
    gemm_out<<<64, 256, 0, stream>>>(ot, wut, bu, out);
}

// Round 2
// 240.876 us; speedup vs baseline: 1.3035x; 1.3035x over previous
//
#include <hip/hip_runtime.h>

// ---------------------------------------------------------------------------
// SelfAttention: B=2,T=2048,D_IN=1024,E=64,H=16, causal, interleaved (E,H)
// cast -> W^T cast -> QKV MFMA GEMM (fused head-layout epilogue, global_load_lds)
//      -> paired-tile flash attention (8 waves, reg-prefetch K/V) -> out GEMM
// ---------------------------------------------------------------------------

typedef __bf16 bf16x8 __attribute__((ext_vector_type(8)));
typedef float f32x4 __attribute__((ext_vector_type(4)));
typedef unsigned short u16;
typedef unsigned int u32;

#define AS1 __attribute__((address_space(1)))
#define AS3 __attribute__((address_space(3)))

__device__ __forceinline__ void gll16(const void* g, void* l) {
    __builtin_amdgcn_global_load_lds((const AS1 u32*)g, (AS3 u32*)l, 16, 0, 0);
}

__device__ __forceinline__ u16 f2bf(float f) {
    union { float f; u32 u; } v; v.f = f;
    u32 r = (v.u + 0x7FFFu + ((v.u >> 16) & 1u)) >> 16;   // RNE
    return (u16)r;
}

#define MM 4096           // B*T
#define DIN 1024

// ---------------- kernel 1: cast inp -> bf16 ----------------
__global__ void cast_x(const float* __restrict__ in, u16* __restrict__ out, int n4) {
    int i = blockIdx.x * blockDim.x + threadIdx.x;
    if (i < n4) {
        float4 f = ((const float4*)in)[i];
        ushort4 o;
        o.x = f2bf(f.x); o.y = f2bf(f.y); o.z = f2bf(f.z); o.w = f2bf(f.w);
        ((ushort4*)out)[i] = o;
    }
}

// ---------------- kernel 2: W[k][n] fp32 -> Wt[n][k] bf16 ----------------
__global__ void transpose_w(const float* __restrict__ Wq, const float* __restrict__ Wk,
                            const float* __restrict__ Wv, const float* __restrict__ Wu,
                            u16* __restrict__ wqt, u16* __restrict__ wkt,
                            u16* __restrict__ wvt, u16* __restrict__ wut) {
    int z = blockIdx.z;
    const float* src; u16* dst; int N;
    if (z == 0)      { src = Wq; dst = wqt; N = 1024; }
    else if (z == 1) { src = Wk; dst = wkt; N = 1024; }
    else if (z == 2) { src = Wv; dst = wvt; N = 1024; }
    else             { src = Wu; dst = wut; N = 64; if (blockIdx.y >= 2) return; }
    __shared__ float lds[32][33];
    int k0 = blockIdx.x * 32, n0 = blockIdx.y * 32;
    int tid = threadIdx.x;
    int c = tid & 31, r0 = tid >> 5;
#pragma unroll
    for (int p = 0; p < 4; ++p) {
        int r = r0 + p * 8;
        lds[r][c] = src[(k0 + r) * N + n0 + c];
    }
    __syncthreads();
#pragma unroll
    for (int p = 0; p < 4; ++p) {
        int nr = r0 + p * 8;
        dst[(n0 + nr) * 1024 + k0 + c] = f2bf(lds[c][nr]);
    }
}

// ---------------- kernel 3: QKV GEMM + fused head layout ----------------
// C[M,N] = Xb[M,K] * Wt[N,K]^T, 128x128 tile, global_load_lds staging.
// z=0/1 (Q/K): write [b][h][t][e];  z=2 (V): write [b][h][e][t] (transposed).
__global__ __launch_bounds__(256) void gemm_qkv(const u16* __restrict__ xb,
                                                const u16* __restrict__ wqt,
                                                const u16* __restrict__ wkt,
                                                const u16* __restrict__ wvt,
                                                u16* __restrict__ qh, u16* __restrict__ kh,
                                                u16* __restrict__ vh) {
    int z = blockIdx.z;
    const u16* wt = (z == 0) ? wqt : (z == 1) ? wkt : wvt;
    u16* dst      = (z == 0) ? qh  : (z == 1) ? kh  : vh;
    __shared__ u16 lA[128 * 32];
    __shared__ u16 lB[128 * 32];
    int tid = threadIdx.x;
    int m0 = blockIdx.x * 128, n0 = blockIdx.y * 128;
    int lane = tid & 63, w = tid >> 6;
    int wr = w >> 1, wc = w & 1;
    int l15 = lane & 15, quad = lane >> 4;
    f32x4 acc[4][4] = {};
    int srow = tid >> 2, scol = (tid & 3) * 8;
#pragma unroll 1
    for (int kk = 0; kk < 32; ++kk) {
        int kb = kk * 32;
        __syncthreads();
#pragma unroll
        for (int pp = 0; pp < 2; ++pp) {
            gll16(xb + (m0 + pp * 64 + srow) * 1024 + kb + scol, lA + (pp * 256 + tid) * 8);
            gll16(wt + (n0 + pp * 64 + srow) * 1024 + kb + scol, lB + (pp * 256 + tid) * 8);
        }
        __syncthreads();
        bf16x8 af[4], bfr[4];
#pragma unroll
        for (int i = 0; i < 4; ++i)
            af[i] = *(const bf16x8*)(lA + (wr * 64 + i * 16 + l15) * 32 + quad * 8);
#pragma unroll
        for (int j = 0; j < 4; ++j)
            bfr[j] = *(const bf16x8*)(lB + (wc * 64 + j * 16 + l15) * 32 + quad * 8);
#pragma unroll
        for (int i = 0; i < 4; ++i)
#pragma unroll
            for (int j = 0; j < 4; ++j)
                acc[i][j] = __builtin_amdgcn_mfma_f32_16x16x32_bf16(af[i], bfr[j], acc[i][j], 0, 0, 0);
    }
    int e0 = (n0 >> 4) + wc * 4;     // e = e0 + j ; h = l15
    int bb = m0 >> 11;
    if (z < 2) {
#pragma unroll
        for (int i = 0; i < 4; ++i)
#pragma unroll
            for (int r = 0; r < 4; ++r) {
                int t = (m0 & 2047) + wr * 64 + i * 16 + quad * 4 + r;
                ushort4 o;
                o.x = f2bf(acc[i][0][r]); o.y = f2bf(acc[i][1][r]);
                o.z = f2bf(acc[i][2][r]); o.w = f2bf(acc[i][3][r]);
                *(ushort4*)(dst + ((bb * 16 + l15) * 2048 + t) * 64 + e0) = o;
            }
    } else {
#pragma unroll
        for (int i = 0; i < 4; ++i)
#pragma unroll
            for (int j = 0; j < 4; ++j) {
                int t4 = (m0 & 2047) + wr * 64 + i * 16 + quad * 4;
                ushort4 o;
                o.x = f2bf(acc[i][j][0]); o.y = f2bf(acc[i][j][1]);
                o.z = f2bf(acc[i][j][2]); o.w = f2bf(acc[i][j][3]);
                *(ushort4*)(dst + ((bb * 16 + l15) * 64 + e0 + j) * 2048 + t4) = o;
            }
    }
}

// ---------------- kernel 4: flash attention, paired 128-row Q tiles ----------------
// grid (8 pairs, 32 b*h) x 512 threads (8 waves, 16 Q-rows each).
// Block p processes qtiles (15-p) then (p): exactly 34 K/V iterations each.
__global__ __launch_bounds__(512) void attn(const u16* __restrict__ qh, const u16* __restrict__ kh,
                                            const u16* __restrict__ vh, u16* __restrict__ ot) {
    __shared__ u16 smem[17408];        // 34816 B total
    u16* sQ = smem;                    // Q: 128x64 (16384 B); as sP: 128x72 (18432 B)
    u16* sK = smem + 9216;             // [k2][64 s][32 e]  (8192 B)
    u16* sV = smem + 13312;            // [s2][64 e][32 s]  (8192 B)
    const int tid = threadIdx.x;
    const int lane = tid & 63, w = tid >> 6;
    const int quad = lane >> 4, l15 = lane & 15;
    const int p = blockIdx.x, by = blockIdx.y;
    const int b = by >> 4, h = by & 15;
    const int ss = (tid >> 2) & 63, sc = (tid & 3) * 8, s2 = tid >> 8;
    const u16* gK0 = kh + (by * 2048 + ss) * 64 + s2 * 32 + sc;   // +jt*4096
    const u16* gV0 = vh + (by * 64 + ss) * 2048 + s2 * 32 + sc;   // +jt*64
    const float SCALE = 0.18033688011112042f;   // log2(e)/sqrt(64)

    for (int hv = 0; hv < 2; ++hv) {
        const int qt = hv ? p : 15 - p;
        const int tq0w = qt * 128 + w * 16;
        __syncthreads();               // prior tile's LDS consumers done
#pragma unroll
        for (int pp = 0; pp < 2; ++pp) {
            int chunk = pp * 512 + tid;
            gll16(qh + (by * 2048 + qt * 128 + (chunk >> 3)) * 64 + (chunk & 7) * 8,
                  sQ + chunk * 8);
        }
        __syncthreads();               // Q in LDS
        bf16x8 aq[2];
        aq[0] = *(const bf16x8*)(sQ + (w * 16 + l15) * 64 + quad * 8);
        aq[1] = *(const bf16x8*)(sQ + (w * 16 + l15) * 64 + 32 + quad * 8);
        float mrow[4], lrow[4];
        f32x4 oacc[4] = {};
#pragma unroll
        for (int r = 0; r < 4; ++r) { mrow[r] = -3e38f; lrow[r] = 0.f; }
        const int nj = 2 * qt + 2;
        uint4 kreg = *(const uint4*)(gK0);
        uint4 vreg = *(const uint4*)(gV0);
        for (int jt = 0; jt < nj; ++jt) {
            __syncthreads();
            *(uint4*)(sK + tid * 8) = kreg;
            *(uint4*)(sV + tid * 8) = vreg;
            __syncthreads();
            if (jt + 1 < nj) {         // prefetch next tile, overlaps compute
                kreg = *(const uint4*)(gK0 + (jt + 1) * 4096);
                vreg = *(const uint4*)(gV0 + (jt + 1) * 64);
            }
            if (jt * 64 > tq0w + 15) continue;   // strip fully masked (wave-uniform)
            f32x4 sacc[4] = {};
#pragma unroll
            for (int j4 = 0; j4 < 4; ++j4)
#pragma unroll
                for (int k2 = 0; k2 < 2; ++k2) {
                    bf16x8 bk = *(const bf16x8*)(sK + k2 * 2048 + (j4 * 16 + l15) * 32 + quad * 8);
                    sacc[j4] = __builtin_amdgcn_mfma_f32_16x16x32_bf16(aq[k2], bk, sacc[j4], 0, 0, 0);
                }
            const bool dz = (jt * 64 + 63 > tq0w);
#pragma unroll
            for (int j4 = 0; j4 < 4; ++j4)
#pragma unroll
                for (int r = 0; r < 4; ++r) {
                    float s = sacc[j4][r] * SCALE;
                    if (dz) {
                        int sg = jt * 64 + j4 * 16 + l15;
                        int tg = tq0w + quad * 4 + r;
                        if (sg > tg) s = -1e30f;
                    }
                    sacc[j4][r] = s;
                }
#pragma unroll
            for (int r = 0; r < 4; ++r) {
                float mx = fmaxf(fmaxf(sacc[0][r], sacc[1][r]), fmaxf(sacc[2][r], sacc[3][r]));
#pragma unroll
                for (int off = 1; off < 16; off <<= 1) mx = fmaxf(mx, __shfl_xor(mx, off, 16));
                float mnew = fmaxf(mrow[r], mx);
                float alpha = __builtin_amdgcn_exp2f(mrow[r] - mnew);
                float rs = 0.f;
#pragma unroll
                for (int j4 = 0; j4 < 4; ++j4) {
                    float pe = __builtin_amdgcn_exp2f(sacc[j4][r] - mnew);
                    sacc[j4][r] = pe; rs += pe;
                }
#pragma unroll
                for (int off = 1; off < 16; off <<= 1) rs += __shfl_xor(rs, off, 16);
                lrow[r] = lrow[r] * alpha + rs;
                mrow[r] = mnew;
#pragma unroll
                for (int e4 = 0; e4 < 4; ++e4) oacc[e4][r] *= alpha;
            }
            // P: C-layout -> per-wave LDS (aliases sQ; barriers make this safe) -> A-layout
            u16* sP = sQ;
#pragma unroll
            for (int j4 = 0; j4 < 4; ++j4)
#pragma unroll
                for (int r = 0; r < 4; ++r)
                    sP[(w * 16 + quad * 4 + r) * 72 + j4 * 16 + l15] = f2bf(sacc[j4][r]);
            bf16x8 ap[2];
            ap[0] = *(const bf16x8*)(sP + (w * 16 + l15) * 72 + quad * 8);
            ap[1] = *(const bf16x8*)(sP + (w * 16 + l15) * 72 + 32 + quad * 8);
#pragma unroll
            for (int e4 = 0; e4 < 4; ++e4)
#pragma unroll
                for (int k2 = 0; k2 < 2; ++k2) {
                    bf16x8 bv = *(const bf16x8*)(sV + k2 * 2048 + (e4 * 16 + l15) * 32 + quad * 8);
                    oacc[e4] = __builtin_amdgcn_mfma_f32_16x16x32_bf16(ap[k2], bv, oacc[e4], 0, 0, 0);
                }
        }
        // epilogue: normalize, store interleaved [b][t][e*16+h]
#pragma unroll
        for (int r = 0; r < 4; ++r) {
            float inv = 1.f / lrow[r];
            int t = qt * 128 + w * 16 + quad * 4 + r;
            int base = (b * 2048 + t) * 1024 + h;
#pragma unroll
            for (int e4 = 0; e4 < 4; ++e4)
                ot[base + (e4 * 16 + l15) * 16] = f2bf(oacc[e4][r] * inv);
        }
    }
}

// ---------------- kernel 5: out = ot[M,1024] @ Wu + bu (fp32 out, N=64) ----------------
__global__ __launch_bounds__(256) void gemm_out(const u16* __restrict__ ot, const u16* __restrict__ wut,
                                                const float* __restrict__ bu, float* __restrict__ out) {
    __shared__ u16 lA[64 * 32];
    __shared__ u16 lB[64 * 32];
    int tid = threadIdx.x, lane = tid & 63, w = tid >> 6;
    int quad = lane >> 4, l15 = lane & 15;
    int m0 = blockIdx.x * 64;
    f32x4 acc[4] = {};
    int row = tid >> 2, kcol = (tid & 3) * 8;
#pragma unroll 1
    for (int kk = 0; kk < 32; ++kk) {
        int kb = kk * 32;
        uint4 a0 = *(const uint4*)(ot + (m0 + row) * 1024 + kb + kcol);
        uint4 b0 = *(const uint4*)(wut + row * 1024 + kb + kcol);
        __syncthreads();
        *(uint4*)(lA + row * 32 + kcol) = a0;
        *(uint4*)(lB + row * 32 + kcol) = b0;
        __syncthreads();
        bf16x8 af = *(const bf16x8*)(lA + (w * 16 + l15) * 32 + quad * 8);
#pragma unroll
        for (int j = 0; j < 4; ++j) {
            bf16x8 bfr = *(const bf16x8*)(lB + (j * 16 + l15) * 32 + quad * 8);
            acc[j] = __builtin_amdgcn_mfma_f32_16x16x32_bf16(af, bfr, acc[j], 0, 0, 0);
        }
    }
#pragma unroll
    for (int j = 0; j < 4; ++j) {
        int n = j * 16 + l15;
        float bias = bu[n];
#pragma unroll
        for (int r = 0; r < 4; ++r) {
            int m = m0 + w * 16 + quad * 4 + r;
            out[m * 64 + n] = acc[j][r] + bias;
        }
    }
}

// ---------------- workspace layout (bytes) ----------------
#define OFF_XB   0u          /* 8 MB; ot aliases this (xb dead after gemm_qkv) */
#define OFF_WQT  8388608u    /* 2 MB */
#define OFF_WKT  10485760u
#define OFF_WVT  12582912u
#define OFF_WUT  14680064u   /* 128 KB */
#define OFF_QH   14811136u   /* 8 MB each */
#define OFF_KH   23199744u
#define OFF_VH   31588352u
#define OFF_OT   OFF_XB

extern "C" void kernel_launch(void* const* d_in, const int* in_sizes, int n_in,
                              void* d_out, int out_size, void* d_ws, size_t ws_size,
                              hipStream_t stream) {
    (void)in_sizes; (void)n_in; (void)out_size; (void)ws_size;
    const float* inp = (const float*)d_in[0];
    // d_in[1] = causal mask — implemented analytically
    const float* Wq = (const float*)d_in[2];
    const float* Wk = (const float*)d_in[3];
    const float* Wv = (const float*)d_in[4];
    const float* Wu = (const float*)d_in[5];
    const float* bu = (const float*)d_in[6];
    float* out = (float*)d_out;
    char* ws = (char*)d_ws;
    u16* xb  = (u16*)(ws + OFF_XB);
    u16* wqt = (u16*)(ws + OFF_WQT);
    u16* wkt = (u16*)(ws + OFF_WKT);
    u16* wvt = (u16*)(ws + OFF_WVT);
    u16* wut = (u16*)(ws + OFF_WUT);
    u16* qh  = (u16*)(ws + OFF_QH);
    u16* kh  = (u16*)(ws + OFF_KH);
    u16* vh  = (u16*)(ws + OFF_VH);
    u16* ot  = (u16*)(ws + OFF_OT);

    cast_x<<<4096, 256, 0, stream>>>(inp, xb, (MM * DIN) / 4);
    transpose_w<<<dim3(32, 32, 4), 256, 0, stream>>>(Wq, Wk, Wv, Wu, wqt, wkt, wvt, wut);
    gemm_qkv<<<dim3(32, 8, 3), 256, 0, stream>>>(xb, wqt, wkt, wvt, qh, kh, vh);
    attn<<<dim3(8, 32), 512, 0, stream>>>(qh, kh, vh, ot);
    gemm_out<<<64, 256, 0, stream>>>(ot, wut, bu, out);
}

// Round 3
// 220.377 us; speedup vs baseline: 1.4248x; 1.0930x over previous
//
#include <hip/hip_runtime.h>

// ---------------------------------------------------------------------------
// SelfAttention: B=2,T=2048,D_IN=1024,E=64,H=16, causal, interleaved (E,H)
// Wt rows permuted to (h*64+e) so QKV GEMM output is head-blocked naturally:
//   qh/kh: [b][t][h*64+e] (plain GEMM out), vh: [b][h][e][t] (fused transpose)
// attn: 64-row Q tiles, paired (p,31-p), 512 blocks (2/CU), reg-prefetch K/V.
// ---------------------------------------------------------------------------

typedef __bf16 bf16x8 __attribute__((ext_vector_type(8)));
typedef float f32x4 __attribute__((ext_vector_type(4)));
typedef unsigned short u16;
typedef unsigned int u32;

#define AS1 __attribute__((address_space(1)))
#define AS3 __attribute__((address_space(3)))

__device__ __forceinline__ void gll16(const void* g, void* l) {
    __builtin_amdgcn_global_load_lds((const AS1 u32*)g, (AS3 u32*)l, 16, 0, 0);
}

__device__ __forceinline__ u16 f2bf(float f) {
    union { float f; u32 u; } v; v.f = f;
    u32 r = (v.u + 0x7FFFu + ((v.u >> 16) & 1u)) >> 16;   // RNE
    return (u16)r;
}

#define MM 4096           // B*T
#define SCALE_LOG2E 0.18033688011112042f   // log2(e)/sqrt(64)

// ---------------- kernel 1: cast inp -> bf16 ----------------
__global__ void cast_x(const float* __restrict__ in, u16* __restrict__ out, int n4) {
    int i = blockIdx.x * blockDim.x + threadIdx.x;
    if (i < n4) {
        float4 f = ((const float4*)in)[i];
        ushort4 o;
        o.x = f2bf(f.x); o.y = f2bf(f.y); o.z = f2bf(f.z); o.w = f2bf(f.w);
        ((ushort4*)out)[i] = o;
    }
}

// ---------------- kernel 2: W[k][n] fp32 -> Wt[perm(n)][k] bf16 ----------------
// For Wq/Wk/Wv (n = e*16+h): perm(n) = (n&15)*64 + (n>>4) = h*64+e.  Wu: identity.
__global__ void transpose_w(const float* __restrict__ Wq, const float* __restrict__ Wk,
                            const float* __restrict__ Wv, const float* __restrict__ Wu,
                            u16* __restrict__ wqt, u16* __restrict__ wkt,
                            u16* __restrict__ wvt, u16* __restrict__ wut) {
    int z = blockIdx.z;
    const float* src; u16* dst; int N;
    if (z == 0)      { src = Wq; dst = wqt; N = 1024; }
    else if (z == 1) { src = Wk; dst = wkt; N = 1024; }
    else if (z == 2) { src = Wv; dst = wvt; N = 1024; }
    else             { src = Wu; dst = wut; N = 64; if (blockIdx.y >= 2) return; }
    __shared__ float lds[32][33];
    int k0 = blockIdx.x * 32, n0 = blockIdx.y * 32;
    int tid = threadIdx.x;
    int c = tid & 31, r0 = tid >> 5;
#pragma unroll
    for (int p = 0; p < 4; ++p) {
        int r = r0 + p * 8;
        lds[r][c] = src[(k0 + r) * N + n0 + c];
    }
    __syncthreads();
#pragma unroll
    for (int p = 0; p < 4; ++p) {
        int n = n0 + r0 + p * 8;
        int rnew = (z < 3) ? (((n & 15) << 6) | (n >> 4)) : n;
        dst[rnew * 1024 + k0 + c] = f2bf(lds[c][n - n0]);
    }
}

// ---------------- kernel 3: QKV GEMM ----------------
// C[M,N] = Xb[M,K] * Wt[N,K]^T, 128x128 tile, global_load_lds staging.
// z=0: Q *SCALE -> [b][t][h*64+e]; z=1: K -> same; z=2: V -> [b][h][e][t].
__global__ __launch_bounds__(256) void gemm_qkv(const u16* __restrict__ xb,
                                                const u16* __restrict__ wqt,
                                                const u16* __restrict__ wkt,
                                                const u16* __restrict__ wvt,
                                                u16* __restrict__ qh, u16* __restrict__ kh,
                                                u16* __restrict__ vh) {
    int z = blockIdx.z;
    const u16* wt = (z == 0) ? wqt : (z == 1) ? wkt : wvt;
    u16* dst      = (z == 0) ? qh  : (z == 1) ? kh  : vh;
    __shared__ u16 lA[128 * 32];
    __shared__ u16 lB[128 * 32];
    int tid = threadIdx.x;
    int m0 = blockIdx.x * 128, n0 = blockIdx.y * 128;
    int lane = tid & 63, w = tid >> 6;
    int wr = w >> 1, wc = w & 1;
    int l15 = lane & 15, quad = lane >> 4;
    f32x4 acc[4][4] = {};
    int srow = tid >> 2, scol = (tid & 3) * 8;
#pragma unroll 1
    for (int kk = 0; kk < 32; ++kk) {
        int kb = kk * 32;
        __syncthreads();
#pragma unroll
        for (int pp = 0; pp < 2; ++pp) {
            gll16(xb + (m0 + pp * 64 + srow) * 1024 + kb + scol, lA + (pp * 256 + tid) * 8);
            gll16(wt + (n0 + pp * 64 + srow) * 1024 + kb + scol, lB + (pp * 256 + tid) * 8);
        }
        __syncthreads();
        bf16x8 af[4], bfr[4];
#pragma unroll
        for (int i = 0; i < 4; ++i)
            af[i] = *(const bf16x8*)(lA + (wr * 64 + i * 16 + l15) * 32 + quad * 8);
#pragma unroll
        for (int j = 0; j < 4; ++j)
            bfr[j] = *(const bf16x8*)(lB + (wc * 64 + j * 16 + l15) * 32 + quad * 8);
#pragma unroll
        for (int i = 0; i < 4; ++i)
#pragma unroll
            for (int j = 0; j < 4; ++j)
                acc[i][j] = __builtin_amdgcn_mfma_f32_16x16x32_bf16(af[i], bfr[j], acc[i][j], 0, 0, 0);
    }
    int bb = m0 >> 11;
    int hb = (n0 >> 6) + wc;                   // head for this wave's n-half
    if (z < 2) {
        float scale = (z == 0) ? SCALE_LOG2E : 1.f;
#pragma unroll
        for (int i = 0; i < 4; ++i)
#pragma unroll
            for (int j = 0; j < 4; ++j)
#pragma unroll
                for (int r = 0; r < 4; ++r) {
                    int m = m0 + wr * 64 + i * 16 + quad * 4 + r;
                    dst[m * 1024 + hb * 64 + j * 16 + l15] = f2bf(acc[i][j][r] * scale);
                }
    } else {
#pragma unroll
        for (int i = 0; i < 4; ++i)
#pragma unroll
            for (int j = 0; j < 4; ++j) {
                int t4 = (m0 & 2047) + wr * 64 + i * 16 + quad * 4;
                ushort4 o;
                o.x = f2bf(acc[i][j][0]); o.y = f2bf(acc[i][j][1]);
                o.z = f2bf(acc[i][j][2]); o.w = f2bf(acc[i][j][3]);
                *(ushort4*)(dst + (((bb * 16 + hb) * 64) + j * 16 + l15) * 2048 + t4) = o;
            }
    }
}

// ---------------- kernel 4: flash attention, paired 64-row Q tiles ----------------
// grid (16 pairs, 32 b*h) x 256 threads (4 waves, 16 Q-rows each) = 512 blocks, 2/CU.
// Block p: qtiles (31-p) then (p) -> nj total = 33 for every block.
__global__ __launch_bounds__(256) void attn(const u16* __restrict__ qh, const u16* __restrict__ kh,
                                            const u16* __restrict__ vh, u16* __restrict__ ot) {
    __shared__ u16 smem[12800];        // 25600 B
    u16* sQ = smem;                    // Q 64x64 (8192 B); as sP: 4 waves x 16 x 72 (9216 B)
    u16* sK = smem + 4608;             // [k2][64 s][32 e] (8192 B)
    u16* sV = smem + 8704;             // [s2][64 e][32 s] (8192 B)
    const int tid = threadIdx.x;
    const int lane = tid & 63, w = tid >> 6;
    const int quad = lane >> 4, l15 = lane & 15;
    const int p = blockIdx.x, by = blockIdx.y;
    const int b = by >> 4, h = by & 15;
    const u16* qbase = qh + (b * 2048) * 1024 + h * 64;
    const u16* kbase = kh + (b * 2048) * 1024 + h * 64;
    const u16* vbase = vh + (by * 64) * 2048;
    // staging coords: chunk c -> (row=c>>3, off=(c&7)*8); two chunks per thread
    const int c0 = tid, c1 = 256 + tid;
    const int r0c = c0 >> 3, o0c = (c0 & 7) * 8;
    const int r1c = c1 >> 3, o1c = (c1 & 7) * 8;
    u16* sKd0 = sK + (o0c >> 5) * 2048 + r0c * 32 + (o0c & 31);
    u16* sKd1 = sK + (o1c >> 5) * 2048 + r1c * 32 + (o1c & 31);
    u16* sVd0 = sV + (o0c >> 5) * 2048 + r0c * 32 + (o0c & 31);
    u16* sVd1 = sV + (o1c >> 5) * 2048 + r1c * 32 + (o1c & 31);
    const u16* kg0 = kbase + r0c * 1024 + o0c;    // + jt*64*1024
    const u16* kg1 = kbase + r1c * 1024 + o1c;
    const u16* vg0 = vbase + r0c * 2048 + o0c;    // + jt*64
    const u16* vg1 = vbase + r1c * 2048 + o1c;

    for (int hv = 0; hv < 2; ++hv) {
        const int qt = hv ? p : 31 - p;
        __syncthreads();               // prior half's sP consumers done
        gll16(qbase + (qt * 64 + r0c) * 1024 + o0c, sQ + c0 * 8);
        gll16(qbase + (qt * 64 + r1c) * 1024 + o1c, sQ + c1 * 8);
        __syncthreads();
        bf16x8 aq[2];
        aq[0] = *(const bf16x8*)(sQ + (w * 16 + l15) * 64 + quad * 8);
        aq[1] = *(const bf16x8*)(sQ + (w * 16 + l15) * 64 + 32 + quad * 8);
        float mrow[4], lrow[4];
        f32x4 oacc[4] = {};
#pragma unroll
        for (int r = 0; r < 4; ++r) { mrow[r] = -3e38f; lrow[r] = 0.f; }
        const int nj = qt + 1;
        uint4 kr0 = *(const uint4*)(kg0);
        uint4 kr1 = *(const uint4*)(kg1);
        uint4 vr0 = *(const uint4*)(vg0);
        uint4 vr1 = *(const uint4*)(vg1);
        for (int jt = 0; jt < nj; ++jt) {
            __syncthreads();
            *(uint4*)sKd0 = kr0; *(uint4*)sKd1 = kr1;
            *(uint4*)sVd0 = vr0; *(uint4*)sVd1 = vr1;
            __syncthreads();
            if (jt + 1 < nj) {         // prefetch next K/V tile, overlaps compute
                kr0 = *(const uint4*)(kg0 + (jt + 1) * 65536);
                kr1 = *(const uint4*)(kg1 + (jt + 1) * 65536);
                vr0 = *(const uint4*)(vg0 + (jt + 1) * 64);
                vr1 = *(const uint4*)(vg1 + (jt + 1) * 64);
            }
            f32x4 sacc[4] = {};
#pragma unroll
            for (int j4 = 0; j4 < 4; ++j4)
#pragma unroll
                for (int k2 = 0; k2 < 2; ++k2) {
                    bf16x8 bk = *(const bf16x8*)(sK + k2 * 2048 + (j4 * 16 + l15) * 32 + quad * 8);
                    sacc[j4] = __builtin_amdgcn_mfma_f32_16x16x32_bf16(aq[k2], bk, sacc[j4], 0, 0, 0);
                }
            if (jt == qt) {            // diagonal tile: causal mask (wave-uniform branch)
#pragma unroll
                for (int j4 = 0; j4 < 4; ++j4)
#pragma unroll
                    for (int r = 0; r < 4; ++r) {
                        int sg = j4 * 16 + l15;
                        int tg = w * 16 + quad * 4 + r;
                        if (sg > tg) sacc[j4][r] = -1e30f;
                    }
            }
#pragma unroll
            for (int r = 0; r < 4; ++r) {
                float mx = fmaxf(fmaxf(sacc[0][r], sacc[1][r]), fmaxf(sacc[2][r], sacc[3][r]));
#pragma unroll
                for (int off = 1; off < 16; off <<= 1) mx = fmaxf(mx, __shfl_xor(mx, off, 16));
                float mnew = fmaxf(mrow[r], mx);
                float alpha = __builtin_amdgcn_exp2f(mrow[r] - mnew);
                float rs = 0.f;
#pragma unroll
                for (int j4 = 0; j4 < 4; ++j4) {
                    float pe = __builtin_amdgcn_exp2f(sacc[j4][r] - mnew);
                    sacc[j4][r] = pe; rs += pe;
                }
#pragma unroll
                for (int off = 1; off < 16; off <<= 1) rs += __shfl_xor(rs, off, 16);
                lrow[r] = lrow[r] * alpha + rs;
                mrow[r] = mnew;
#pragma unroll
                for (int e4 = 0; e4 < 4; ++e4) oacc[e4][r] *= alpha;
            }
            // P: C-layout -> per-wave LDS strip (aliases sQ) -> A-layout
            u16* sP = sQ;
#pragma unroll
            for (int j4 = 0; j4 < 4; ++j4)
#pragma unroll
                for (int r = 0; r < 4; ++r)
                    sP[(w * 16 + quad * 4 + r) * 72 + j4 * 16 + l15] = f2bf(sacc[j4][r]);
            bf16x8 ap[2];
            ap[0] = *(const bf16x8*)(sP + (w * 16 + l15) * 72 + quad * 8);
            ap[1] = *(const bf16x8*)(sP + (w * 16 + l15) * 72 + 32 + quad * 8);
#pragma unroll
            for (int e4 = 0; e4 < 4; ++e4)
#pragma unroll
                for (int k2 = 0; k2 < 2; ++k2) {
                    bf16x8 bv = *(const bf16x8*)(sV + k2 * 2048 + (e4 * 16 + l15) * 32 + quad * 8);
                    oacc[e4] = __builtin_amdgcn_mfma_f32_16x16x32_bf16(ap[k2], bv, oacc[e4], 0, 0, 0);
                }
        }
        // epilogue: normalize, store interleaved [b][t][e*16+h]
#pragma unroll
        for (int r = 0; r < 4; ++r) {
            float inv = 1.f / lrow[r];
            int t = qt * 64 + w * 16 + quad * 4 + r;
            int base = (b * 2048 + t) * 1024 + h;
#pragma unroll
            for (int e4 = 0; e4 < 4; ++e4)
                ot[base + (e4 * 16 + l15) * 16] = f2bf(oacc[e4][r] * inv);
        }
    }
}

// ---------------- kernel 5: out = ot[M,1024] @ Wu + bu ----------------
// 256 blocks x 16 rows; 4 waves split K (256 each); direct 16B frag loads, LDS reduce.
__global__ __launch_bounds__(256) void gemm_out(const u16* __restrict__ ot, const u16* __restrict__ wut,
                                                const float* __restrict__ bu, float* __restrict__ out) {
    __shared__ float red[4][1088];     // [w][n*17 + m]
    int tid = threadIdx.x, lane = tid & 63, w = tid >> 6;
    int quad = lane >> 4, l15 = lane & 15;
    int m0 = blockIdx.x * 16;
    f32x4 acc[4] = {};
    const u16* aptr = ot + (m0 + l15) * 1024 + w * 256 + quad * 8;
    const u16* bptr = wut + l15 * 1024 + w * 256 + quad * 8;
#pragma unroll
    for (int kk = 0; kk < 8; ++kk) {
        bf16x8 af = *(const bf16x8*)(aptr + kk * 32);
#pragma unroll
        for (int j = 0; j < 4; ++j) {
            bf16x8 bfr = *(const bf16x8*)(bptr + j * 16 * 1024 + kk * 32);
            acc[j] = __builtin_amdgcn_mfma_f32_16x16x32_bf16(af, bfr, acc[j], 0, 0, 0);
        }
    }
#pragma unroll
    for (int j = 0; j < 4; ++j)
#pragma unroll
        for (int r = 0; r < 4; ++r)
            red[w][(j * 16 + l15) * 17 + quad * 4 + r] = acc[j][r];
    __syncthreads();
    int n = tid & 63, mq = tid >> 6;
    float bias = bu[n];
#pragma unroll
    for (int i = 0; i < 4; ++i) {
        int m = mq * 4 + i;
        float s = red[0][n * 17 + m] + red[1][n * 17 + m] + red[2][n * 17 + m] + red[3][n * 17 + m];
        out[(m0 + m) * 64 + n] = s + bias;
    }
}

// ---------------- workspace layout (bytes) ----------------
#define OFF_XB   0u          /* 8 MB; ot aliases this (xb dead after gemm_qkv) */
#define OFF_WQT  8388608u    /* 2 MB */
#define OFF_WKT  10485760u
#define OFF_WVT  12582912u
#define OFF_WUT  14680064u   /* 128 KB */
#define OFF_QH   14811136u   /* 8 MB each */
#define OFF_KH   23199744u
#define OFF_VH   31588352u
#define OFF_OT   OFF_XB

extern "C" void kernel_launch(void* const* d_in, const int* in_sizes, int n_in,
                              void* d_out, int out_size, void* d_ws, size_t ws_size,
                              hipStream_t stream) {
    (void)in_sizes; (void)n_in; (void)out_size; (void)ws_size;
    const float* inp = (const float*)d_in[0];
    // d_in[1] = causal mask — implemented analytically
    const float* Wq = (const float*)d_in[2];
    const float* Wk = (const float*)d_in[3];
    const float* Wv = (const float*)d_in[4];
    const float* Wu = (const float*)d_in[5];
    const float* bu = (const float*)d_in[6];
    float* out = (float*)d_out;
    char* ws = (char*)d_ws;
    u16* xb  = (u16*)(ws + OFF_XB);
    u16* wqt = (u16*)(ws + OFF_WQT);
    u16* wkt = (u16*)(ws + OFF_WKT);
    u16* wvt = (u16*)(ws + OFF_WVT);
    u16* wut = (u16*)(ws + OFF_WUT);
    u16* qh  = (u16*)(ws + OFF_QH);
    u16* kh  = (u16*)(ws + OFF_KH);
    u16* vh  = (u16*)(ws + OFF_VH);
    u16* ot  = (u16*)(ws + OFF_OT);

    cast_x<<<4096, 256, 0, stream>>>(inp, xb, (MM * 1024) / 4);
    transpose_w<<<dim3(32, 32, 4), 256, 0, stream>>>(Wq, Wk, Wv, Wu, wqt, wkt, wvt, wut);
    gemm_qkv<<<dim3(32, 8, 3), 256, 0, stream>>>(xb, wqt, wkt, wvt, qh, kh, vh);
    attn<<<dim3(16, 32), 256, 0, stream>>>(qh, kh, vh, ot);
    gemm_out<<<256, 256, 0, stream>>>(ot, wut, bu, out);
}